// Round 5
// baseline (193.811 us; speedup 1.0000x reference)
//
#include <hip/hip_runtime.h>
#include <hip/hip_bf16.h>

#define BB 8
#define CC 512
#define NN 2048
#define DD 64

typedef __attribute__((ext_vector_type(8))) _Float16 f16x8;
typedef __attribute__((ext_vector_type(4))) _Float16 f16x4;
typedef __attribute__((ext_vector_type(4))) float f32x4;

// ---- workspace layout (bytes) ----
#define WS_WF 0u          // Wf  f16 [640][512]       0.65 MB
#define WS_FT 1048576u    // fT  f16 [b][n][64]       2 MB
#define WS_GT 3145728u    // gT  f16 [b][m][64]       2 MB
#define WS_H  5242880u    // h'  f16 [b][c][n]        16 MB (mask folded)
#define WS_M  22020096u   // M partials f32 [4][b][m] 256 KB
#define WS_S  22282240u   // S partials f32 [4][b][m] 256 KB

// ---- attn2 dynamic LDS (bytes): 3x h(32K) + 3x fT(8K) + 2x bt(16K) = 152K ----
#define HSOFF(bf) ((bf) * 32768)
#define FSOFF(bf) (98304 + (bf) * 8192)
#define BTOFF(bf) (122880 + (bf) * 16384)
#define LDS2B 155648

static __device__ __forceinline__ void gload_lds16(const void* g, void* l) {
    __builtin_amdgcn_global_load_lds(
        (const __attribute__((address_space(1))) void*)g,
        (__attribute__((address_space(3))) void*)l, 16, 0, 0);
}

static __device__ __forceinline__ void hard_barrier() {
    __builtin_amdgcn_sched_barrier(0);
    __builtin_amdgcn_s_barrier();
    __builtin_amdgcn_sched_barrier(0);
}

// =================== Kernel 0: W -> fp16 ===================
__global__ __launch_bounds__(256) void wconv_kernel(
    const float* __restrict__ Wq, const float* __restrict__ Wk,
    const float* __restrict__ Wv, _Float16* __restrict__ Wf)
{
    int e = (blockIdx.x * 256 + threadIdx.x) * 8;
    const float* src;
    if (e < 32768) src = Wq + e;
    else if (e < 65536) src = Wk + (e - 32768);
    else src = Wv + (e - 65536);
    float4 v0 = *reinterpret_cast<const float4*>(src);
    float4 v1 = *reinterpret_cast<const float4*>(src + 4);
    f16x8 o = {(_Float16)v0.x, (_Float16)v0.y, (_Float16)v0.z, (_Float16)v0.w,
               (_Float16)v1.x, (_Float16)v1.y, (_Float16)v1.z, (_Float16)v1.w};
    *reinterpret_cast<f16x8*>(Wf + e) = o;
}

// =================== Kernel 1: projections (in-register 4x4 transpose) ===================
// grid (32 nb, 8 b), 512 thr, 2 blocks/CU. xs[n][512 c] f16, chunk(8 f16) ^= n&7.
__global__ __launch_bounds__(512, 2) void proj_kernel(
    const float* __restrict__ x, const _Float16* __restrict__ Wf,
    const float* __restrict__ mask,
    _Float16* __restrict__ fT, _Float16* __restrict__ gT, _Float16* __restrict__ h)
{
    const int nb = blockIdx.x, b = blockIdx.y;
    const int n0 = nb * 64;
    const int t = threadIdx.x, w = t >> 6, l = t & 63, lo = l & 15, hi = l >> 4;

    __shared__ _Float16 xs[64 * 512];

    const float* xb = x + (size_t)b * CC * NN + n0;
    {
        const int nq = t & 15, cqi = t >> 4;
        #pragma unroll
        for (int p = 0; p < 4; p++) {
            int c0 = 128 * p + 4 * cqi;
            float4 v0 = *reinterpret_cast<const float4*>(xb + (size_t)(c0 + 0) * NN + 4 * nq);
            float4 v1 = *reinterpret_cast<const float4*>(xb + (size_t)(c0 + 1) * NN + 4 * nq);
            float4 v2 = *reinterpret_cast<const float4*>(xb + (size_t)(c0 + 2) * NN + 4 * nq);
            float4 v3 = *reinterpret_cast<const float4*>(xb + (size_t)(c0 + 3) * NN + 4 * nq);
            int cc = c0 >> 3, cb = c0 & 7;
            f16x4 t0 = {(_Float16)v0.x, (_Float16)v1.x, (_Float16)v2.x, (_Float16)v3.x};
            f16x4 t1 = {(_Float16)v0.y, (_Float16)v1.y, (_Float16)v2.y, (_Float16)v3.y};
            f16x4 t2 = {(_Float16)v0.z, (_Float16)v1.z, (_Float16)v2.z, (_Float16)v3.z};
            f16x4 t3 = {(_Float16)v0.w, (_Float16)v1.w, (_Float16)v2.w, (_Float16)v3.w};
            int n = 4 * nq;
            *reinterpret_cast<f16x4*>(&xs[(n + 0) * 512 + (((cc ^ ((n + 0) & 7)) << 3) | cb)]) = t0;
            *reinterpret_cast<f16x4*>(&xs[(n + 1) * 512 + (((cc ^ ((n + 1) & 7)) << 3) | cb)]) = t1;
            *reinterpret_cast<f16x4*>(&xs[(n + 2) * 512 + (((cc ^ ((n + 2) & 7)) << 3) | cb)]) = t2;
            *reinterpret_cast<f16x4*>(&xs[(n + 3) * 512 + (((cc ^ ((n + 3) & 7)) << 3) | cb)]) = t3;
        }
    }
    __syncthreads();

    f32x4 acc[5][4];
    #pragma unroll
    for (int i = 0; i < 5; i++)
        #pragma unroll
        for (int j = 0; j < 4; j++) acc[i][j] = (f32x4){0.f, 0.f, 0.f, 0.f};

    #pragma unroll 4
    for (int ks = 0; ks < 16; ks++) {
        f16x8 bfr[4];
        #pragma unroll
        for (int nf = 0; nf < 4; nf++) {
            int row = 16 * nf + lo;
            bfr[nf] = *reinterpret_cast<const f16x8*>(
                &xs[row * 512 + (((4 * ks + hi) ^ (row & 7)) << 3)]);
        }
        #pragma unroll
        for (int rf = 0; rf < 5; rf++) {
            f16x8 af = *reinterpret_cast<const f16x8*>(
                Wf + (size_t)(16 * (w + 8 * rf) + lo) * CC + 32 * ks + 8 * hi);
            #pragma unroll
            for (int nf = 0; nf < 4; nf++)
                acc[rf][nf] = __builtin_amdgcn_mfma_f32_16x16x32_f16(af, bfr[nf], acc[rf][nf], 0, 0, 0);
        }
    }

    float mask4[4];
    #pragma unroll
    for (int nf = 0; nf < 4; nf++) mask4[nf] = mask[(size_t)b * NN + n0 + 16 * nf + lo];

    #pragma unroll
    for (int rf = 0; rf < 5; rf++) {
        int Rb = 16 * (w + 8 * rf);
        #pragma unroll
        for (int nf = 0; nf < 4; nf++) {
            int n = n0 + 16 * nf + lo;
            if (Rb < 64) {
                f16x4 v = {(_Float16)acc[rf][nf][0], (_Float16)acc[rf][nf][1],
                           (_Float16)acc[rf][nf][2], (_Float16)acc[rf][nf][3]};
                *reinterpret_cast<f16x4*>(&fT[((size_t)b * NN + n) * DD + Rb + 4 * hi]) = v;
            } else if (Rb < 128) {
                f16x4 v = {(_Float16)acc[rf][nf][0], (_Float16)acc[rf][nf][1],
                           (_Float16)acc[rf][nf][2], (_Float16)acc[rf][nf][3]};
                *reinterpret_cast<f16x4*>(&gT[((size_t)b * NN + n) * DD + (Rb - 64) + 4 * hi]) = v;
            } else {
                int cr = Rb - 128 + 4 * hi;
                #pragma unroll
                for (int j = 0; j < 4; j++)
                    h[((size_t)b * CC + cr + j) * NN + n] = (_Float16)(acc[rf][nf][j] * mask4[nf]);
            }
        }
    }
}

// =================== Kernel 2a: split-K x4 column max + masked exp-sum ===================
// grid 1024: b=bid&7, mb=(bid>>3)&31 (m-tile 64), ns=bid>>8 (n-quarter). 8 waves, 1 n-tile each.
__global__ __launch_bounds__(512) void stats_kernel(
    const _Float16* __restrict__ fT, const _Float16* __restrict__ gT,
    const float* __restrict__ mask, float* __restrict__ Mp, float* __restrict__ Sp)
{
    const int bid = blockIdx.x;
    const int b = bid & 7, mb = (bid >> 3) & 31, ns = bid >> 8;
    const int m0 = mb * 64;
    const int t = threadIdx.x, w = t >> 6, l = t & 63, lo = l & 15, hi = l >> 4;

    __shared__ float masks_l[512];
    __shared__ float sm[8][64], ss[8][64];

    masks_l[t] = mask[(size_t)b * NN + ns * 512 + t];
    __syncthreads();

    const _Float16* gTb = gT + (size_t)b * NN * DD;
    const _Float16* fTb = fT + ((size_t)b * NN + ns * 512 + 64 * w) * DD;

    f16x8 bq[4][2];
    #pragma unroll
    for (int mf = 0; mf < 4; mf++)
        #pragma unroll
        for (int kk = 0; kk < 2; kk++)
            bq[mf][kk] = *reinterpret_cast<const f16x8*>(
                gTb + (size_t)(m0 + 16 * mf + lo) * DD + 32 * kk + 8 * hi);

    f16x8 afr[4][2];
    #pragma unroll
    for (int rf = 0; rf < 4; rf++)
        #pragma unroll
        for (int kk = 0; kk < 2; kk++)
            afr[rf][kk] = *reinterpret_cast<const f16x8*>(
                fTb + (size_t)(16 * rf + lo) * DD + 32 * kk + 8 * hi);

    float m_run[4], s_run[4];
    #pragma unroll
    for (int mf = 0; mf < 4; mf++) {
        f32x4 s4[4];
        #pragma unroll
        for (int rf = 0; rf < 4; rf++) {
            f32x4 a4 = (f32x4){0.f, 0.f, 0.f, 0.f};
            a4 = __builtin_amdgcn_mfma_f32_16x16x32_f16(afr[rf][0], bq[mf][0], a4, 0, 0, 0);
            a4 = __builtin_amdgcn_mfma_f32_16x16x32_f16(afr[rf][1], bq[mf][1], a4, 0, 0, 0);
            s4[rf] = a4;
        }
        float mx = -1e30f;
        #pragma unroll
        for (int rf = 0; rf < 4; rf++)
            #pragma unroll
            for (int j = 0; j < 4; j++) mx = fmaxf(mx, s4[rf][j]);
        float sum = 0.f;
        #pragma unroll
        for (int rf = 0; rf < 4; rf++)
            #pragma unroll
            for (int j = 0; j < 4; j++)
                sum += masks_l[64 * w + 16 * rf + 4 * hi + j] * __expf(s4[rf][j] - mx);
        m_run[mf] = mx; s_run[mf] = sum;
    }
    #pragma unroll
    for (int mf = 0; mf < 4; mf++) {
        #pragma unroll
        for (int d = 16; d <= 32; d <<= 1) {
            float om = __shfl_xor(m_run[mf], d);
            float os = __shfl_xor(s_run[mf], d);
            float nm = fmaxf(m_run[mf], om);
            s_run[mf] = s_run[mf] * __expf(m_run[mf] - nm) + os * __expf(om - nm);
            m_run[mf] = nm;
        }
    }
    if (l < 16) {
        #pragma unroll
        for (int mf = 0; mf < 4; mf++) { sm[w][16 * mf + l] = m_run[mf]; ss[w][16 * mf + l] = s_run[mf]; }
    }
    __syncthreads();
    if (t < 64) {
        float M = -1e30f;
        #pragma unroll
        for (int w8 = 0; w8 < 8; w8++) M = fmaxf(M, sm[w8][t]);
        float S = 0.f;
        #pragma unroll
        for (int w8 = 0; w8 < 8; w8++) S += ss[w8][t] * __expf(sm[w8][t] - M);
        Mp[(size_t)(ns * 8 + b) * NN + m0 + t] = M;
        Sp[(size_t)(ns * 8 + b) * NN + m0 + t] = S;
    }
}

// =================== Kernel 2b: beta + PV + residual (3-deep counted-vmcnt pipeline) ===
// grid 256: b=bid&7, mb=(bid>>3)&15 (m-tile 128), cs=bid>>7 (c-half 256).
// scores: wave = (n-frag w&3, m-half w>>2). PV: wave = (c-64 w&3, m-64 w>>2).
__global__ __launch_bounds__(512, 1) void attn2_kernel(
    const _Float16* __restrict__ fT, const _Float16* __restrict__ gT,
    const _Float16* __restrict__ h, const float* __restrict__ x,
    const float* __restrict__ Mp, const float* __restrict__ Sp,
    const float* __restrict__ gamma, float* __restrict__ out)
{
    extern __shared__ __align__(16) char smem[];
    const int bid = blockIdx.x;
    const int b = bid & 7, mb = (bid >> 3) & 15, cs = bid >> 7;
    const int m0 = mb * 128, cbase = cs * 256;
    const int t = threadIdx.x, w = t >> 6, l = t & 63, lo = l & 15, hi = l >> 4;
    const int r3 = l >> 3, c3 = l & 7, sch = c3 ^ r3;
    const int sn = 16 * (w & 3), smg = 64 * (w >> 2);
    const int cg = w & 3, mg = w >> 2;

    const _Float16* hb = h + (size_t)b * CC * NN;
    const _Float16* fTb = fT + (size_t)b * NN * DD;

    // preload query frags + merge 4 stats partials
    f16x8 bq[4][2]; float Mr[4], iSr[4];
    #pragma unroll
    for (int mf = 0; mf < 4; mf++) {
        int m = m0 + smg + 16 * mf + lo;
        #pragma unroll
        for (int kk = 0; kk < 2; kk++)
            bq[mf][kk] = *reinterpret_cast<const f16x8*>(
                gT + ((size_t)b * NN + m) * DD + 32 * kk + 8 * hi);
        float Ms[4], Ss[4];
        #pragma unroll
        for (int ns = 0; ns < 4; ns++) {
            Ms[ns] = Mp[(size_t)(ns * 8 + b) * NN + m];
            Ss[ns] = Sp[(size_t)(ns * 8 + b) * NN + m];
        }
        float M = fmaxf(fmaxf(Ms[0], Ms[1]), fmaxf(Ms[2], Ms[3]));
        float S = Ss[0] * __expf(Ms[0] - M) + Ss[1] * __expf(Ms[1] - M)
                + Ss[2] * __expf(Ms[2] - M) + Ss[3] * __expf(Ms[3] - M);
        Mr[mf] = M; iSr[mf] = 1.0f / (S + 1e-20f);
    }

    f32x4 o[4][4];
    #pragma unroll
    for (int ci = 0; ci < 4; ci++)
        #pragma unroll
        for (int mi = 0; mi < 4; mi++) o[ci][mi] = (f32x4){0.f, 0.f, 0.f, 0.f};

    // STAGE: fT (1 load) then h (4 loads) -> 5 per wave per tile
    #define STAGE(ti, bs) do {                                                          \
        char* _fd = smem + FSOFF(bs) + (8 * w) * 128;                                   \
        const _Float16* _fs = fTb + (size_t)((ti) * 64 + 8 * w + r3) * DD + sch * 8;    \
        gload_lds16((const void*)_fs, (void*)_fd);                                      \
        char* _hd = smem + HSOFF(bs) + (32 * w) * 128;                                  \
        const _Float16* _hs = hb + (size_t)(cbase + 32 * w + r3) * NN + (ti) * 64 + sch * 8; \
        _Pragma("unroll")                                                               \
        for (int _q = 0; _q < 4; _q++)                                                  \
            gload_lds16((const void*)(_hs + (size_t)(8 * _q) * NN), (void*)(_hd + _q * 1024)); \
    } while (0)

    STAGE(0, 0);
    STAGE(1, 1);

    #pragma unroll 1
    for (int i = 0; i < 32; i++) {
        if (i == 31) asm volatile("s_waitcnt vmcnt(0)" ::: "memory");
        else         asm volatile("s_waitcnt vmcnt(5)" ::: "memory");
        hard_barrier();                         // stage i visible to all waves
        if (i <= 29) STAGE(i + 2, (i + 2) % 3);

        // ---- scores(i): n-frag sn, m-half smg ----
        char* fsb = smem + FSOFF(i % 3);
        char* btb = smem + BTOFF(i & 1);
        {
            int arow = sn + lo;
            f16x8 af0 = *reinterpret_cast<const f16x8*>(fsb + arow * 128 + ((hi ^ (lo & 7)) << 4));
            f16x8 af1 = *reinterpret_cast<const f16x8*>(fsb + arow * 128 + (((4 + hi) ^ (lo & 7)) << 4));
            #pragma unroll
            for (int mf = 0; mf < 4; mf++) {
                f32x4 a4 = (f32x4){0.f, 0.f, 0.f, 0.f};
                a4 = __builtin_amdgcn_mfma_f32_16x16x32_f16(af0, bq[mf][0], a4, 0, 0, 0);
                a4 = __builtin_amdgcn_mfma_f32_16x16x32_f16(af1, bq[mf][1], a4, 0, 0, 0);
                f16x4 ev;
                #pragma unroll
                for (int j = 0; j < 4; j++)
                    ev[j] = (_Float16)(__expf(a4[j] - Mr[mf]) * iSr[mf]);
                int ml = smg + 16 * mf + lo;
                int chunk = (2 * (w & 3) + (hi >> 1)) ^ (lo & 7);
                *reinterpret_cast<f16x4*>(btb + ml * 128 + chunk * 16 + (hi & 1) * 8) = ev;
            }
        }
        asm volatile("s_waitcnt lgkmcnt(0)" ::: "memory");
        hard_barrier();                         // beta(i) ready

        // ---- PV(i): c-64 cg, m-64 mg ----
        char* hsb = smem + HSOFF(i % 3);
        #pragma unroll
        for (int kk = 0; kk < 2; kk++) {
            f16x8 bb[4];
            #pragma unroll
            for (int mi = 0; mi < 4; mi++) {
                int ml = 64 * mg + 16 * mi + lo;
                bb[mi] = *reinterpret_cast<const f16x8*>(
                    btb + ml * 128 + (((4 * kk + hi) ^ (lo & 7)) << 4));
            }
            #pragma unroll
            for (int ci = 0; ci < 4; ci++) {
                int crow = 64 * cg + 16 * ci + lo;
                f16x8 ah = *reinterpret_cast<const f16x8*>(
                    hsb + crow * 128 + (((4 * kk + hi) ^ (lo & 7)) << 4));
                #pragma unroll
                for (int mi = 0; mi < 4; mi++)
                    o[ci][mi] = __builtin_amdgcn_mfma_f32_16x16x32_f16(ah, bb[mi], o[ci][mi], 0, 0, 0);
            }
        }
    }
    #undef STAGE

    // ---- epilogue: residual add, direct stores (full 64B sectors per instr) ----
    const float gm = gamma[0];
    const float* xb = x + (size_t)b * CC * NN;
    float* outb = out + (size_t)b * CC * NN;
    #pragma unroll
    for (int ci = 0; ci < 4; ci++)
        #pragma unroll
        for (int mi = 0; mi < 4; mi++)
            #pragma unroll
            for (int j = 0; j < 4; j++) {
                int c = cbase + 64 * cg + 16 * ci + 4 * hi + j;
                int m = m0 + 64 * mg + 16 * mi + lo;
                size_t idx = (size_t)c * NN + m;
                outb[idx] = gm * o[ci][mi][j] + xb[idx];
            }
}

extern "C" void kernel_launch(void* const* d_in, const int* in_sizes, int n_in,
                              void* d_out, int out_size, void* d_ws, size_t ws_size,
                              hipStream_t stream) {
    (void)in_sizes; (void)n_in; (void)out_size; (void)ws_size;
    const float* x     = (const float*)d_in[0];
    const float* mask  = (const float*)d_in[1];
    const float* Wq    = (const float*)d_in[2];
    const float* Wk    = (const float*)d_in[3];
    const float* Wv    = (const float*)d_in[4];
    const float* gamma = (const float*)d_in[5];
    float* out = (float*)d_out;

    char* ws = (char*)d_ws;
    _Float16* Wf = (_Float16*)(ws + WS_WF);
    _Float16* fT = (_Float16*)(ws + WS_FT);
    _Float16* gT = (_Float16*)(ws + WS_GT);
    _Float16* h  = (_Float16*)(ws + WS_H);
    float* Mp = (float*)(ws + WS_M);
    float* Sp = (float*)(ws + WS_S);

    wconv_kernel<<<160, 256, 0, stream>>>(Wq, Wk, Wv, Wf);
    proj_kernel<<<dim3(32, 8), 512, 0, stream>>>(x, Wf, mask, fT, gT, h);
    stats_kernel<<<1024, 512, 0, stream>>>(fT, gT, mask, Mp, Sp);
    hipFuncSetAttribute((const void*)attn2_kernel,
                        hipFuncAttributeMaxDynamicSharedMemorySize, LDS2B);
    attn2_kernel<<<256, 512, LDS2B, stream>>>(fT, gT, h, x, Mp, Sp, gamma, out);
}